// Round 2
// baseline (1643.139 us; speedup 1.0000x reference)
//
#include <hip/hip_runtime.h>
#include <hip/hip_bf16.h>

// GraphCAD forward on MI355X. All float I/O is f32.
// R8->R9: k_nodeup was latency-bound (VALUBusy 9%, HBM 16%, occ 18%): the
// 4-wide gather loop kept only ~4 loads in flight per wave. Now: masked
// 16-wide batched gather (all src/ew loads issued, then all 16 x-row gathers
// in flight, then FMA), f32 x source (xin / x32 mirror; acc + GIN matvec stay
// f64). Layer-1 edge decisions complete before k_nodeup<1>, so the x32
// rounding (6e-8 rel) touches only continuous outputs; layer-0 perturbation
// into layer-1 scores is ~1e-8, far below the jax-f32 gap that already passes.

#define D 64
#define BSZ 16
#define NPG 4096
#define NN (BSZ * NPG)   // 65536 nodes
#define NE (NN * 16)     // 1048576 edges
#define NL 2
#define NTILE (NE / 64)  // 16384

#define FIXTH 2e-3f
#define FLAGCAP 65536

// output layout (elements, f32)
#define OUT_X  0u
#define OUT_EW 4194304u
#define OUT_C  5242880u
#define OUT_XL 5243904u
#define OUT_CL 9438208u
#define OUT_PA 9439232u

__device__ __forceinline__ void atomAdd64(double* p, double v) { unsafeAtomicAdd(p, v); }

// ================= CSR build (dst is a static input; rebuilt per call) ======
__global__ __launch_bounds__(256) void k_deg(const int* __restrict__ edst,
                                             int* __restrict__ cnt) {
    int stride = gridDim.x * 256;
    for (int e = blockIdx.x * 256 + threadIdx.x; e < NE; e += stride)
        atomicAdd(&cnt[edst[e]], 1);
}

__global__ __launch_bounds__(256) void k_scan1(const int* __restrict__ cnt,
                                               int* __restrict__ rowptr,
                                               int* __restrict__ bsum) {
    __shared__ int sd[256];
    const int b = blockIdx.x, t = threadIdx.x;
    const int v = cnt[b * 256 + t];
    sd[t] = v;
    __syncthreads();
    for (int off = 1; off < 256; off <<= 1) {
        int tmp = (t >= off) ? sd[t - off] : 0;
        __syncthreads();
        sd[t] += tmp;
        __syncthreads();
    }
    rowptr[b * 256 + t] = sd[t] - v;  // exclusive
    if (t == 255) bsum[b] = sd[255];
}

__global__ __launch_bounds__(256) void k_scan2(int* __restrict__ bsum) {
    __shared__ int sd[256];
    const int t = threadIdx.x;
    const int v = bsum[t];
    sd[t] = v;
    __syncthreads();
    for (int off = 1; off < 256; off <<= 1) {
        int tmp = (t >= off) ? sd[t - off] : 0;
        __syncthreads();
        sd[t] += tmp;
        __syncthreads();
    }
    bsum[t] = sd[t] - v;  // exclusive
}

__global__ __launch_bounds__(256) void k_scan3(const int* __restrict__ bsum,
                                               int* __restrict__ rowptr,
                                               int* __restrict__ cursor) {
    const int i = blockIdx.x * 256 + threadIdx.x;
    const int r = rowptr[i] + bsum[blockIdx.x];
    rowptr[i] = r;
    cursor[i] = r;
    if (i == 0) rowptr[NN] = NE;
}

// fill CSR: slot -> original edge (eord), src (src_csr), dst (dst_csr).
__global__ __launch_bounds__(256) void k_fill(const int* __restrict__ esrc,
                                              const int* __restrict__ edst,
                                              int* __restrict__ cursor,
                                              int* __restrict__ eord,
                                              int* __restrict__ src_csr,
                                              int* __restrict__ dst_csr) {
    int stride = gridDim.x * 256;
    for (int e = blockIdx.x * 256 + threadIdx.x; e < NE; e += stride) {
        const int d = edst[e];
        int pos = atomicAdd(&cursor[d], 1);
        eord[pos] = e;
        src_csr[pos] = esrc[e];
        dst_csr[pos] = d;
    }
}

// ---- initial centroid: per-graph mean of x (f32 in, f64 out) ----
__global__ __launch_bounds__(256) void k_centroid0(const float* __restrict__ xin,
                                                   double* __restrict__ c64) {
    int g = blockIdx.x, tid = threadIdx.x;
    int r = tid >> 6, f = tid & 63;
    __shared__ double cr[4][D];
    double s = 0.0;
    for (int k = 0; k < NPG / 4; ++k) {
        size_t n = (size_t)g * NPG + (size_t)(4 * k + r);
        s += (double)xin[n * D + f];
    }
    cr[r][f] = s;
    __syncthreads();
    if (tid < D)
        c64[g * D + tid] = (cr[0][tid] + cr[1][tid] + cr[2][tid] + cr[3][tid]) * (1.0 / NPG);
}

// ---- qb = c @ W1b, qc = c @ W1c (per graph, f64) ----
__global__ __launch_bounds__(256) void k_qbc(const double* __restrict__ c64,
                                             const float* __restrict__ epW1,
                                             double* __restrict__ qb, double* __restrict__ qc) {
    int gj = blockIdx.x * 256 + threadIdx.x;
    if (gj >= BSZ * D) return;
    int g = gj >> 6, j = gj & 63;
    double sb = 0.0, sc = 0.0;
#pragma unroll
    for (int i = 0; i < D; ++i) {
        double cv = c64[g * D + i];
        sb += cv * (double)epW1[(D + i) * D + j];
        sc += cv * (double)epW1[(2 * D + i) * D + j];
    }
    qb[gj] = sb;
    qc[gj] = sc;
}

// ---- P'_b = x@W1b - qb[g], P'_c = x@W1c - qc[g]; f64 compute, f32 store ----
template <int LAYER>
__global__ __launch_bounds__(256) void k_P(const float* __restrict__ xin,
                                           const double* __restrict__ x64,
                                           const float* __restrict__ epW1,
                                           const double* __restrict__ qb,
                                           const double* __restrict__ qc,
                                           float* __restrict__ Pb, float* __restrict__ Pc,
                                           double* __restrict__ bnacc) {
    if (blockIdx.x == 0 && threadIdx.x < 128) bnacc[threadIdx.x] = 0.0;
    __shared__ double wb[D * D];
    __shared__ double wc[D * D];
    __shared__ double xrow[4][D];
    int tid = threadIdx.x, w = tid >> 6, j = tid & 63;
    for (int idx = tid; idx < D * D; idx += 256) {
        int i = idx >> 6, c = idx & 63;
        wb[idx] = (double)epW1[(D + i) * D + c];
        wc[idx] = (double)epW1[(2 * D + i) * D + c];
    }
    __syncthreads();
    for (int grp = blockIdx.x; grp < NN / 4; grp += gridDim.x) {
        size_t n = (size_t)grp * 4 + w;
        xrow[w][j] = (LAYER == 0) ? (double)xin[n * D + j] : x64[n * D + j];
        __syncthreads();
        double pb = 0.0, pc = 0.0;
#pragma unroll
        for (int i = 0; i < D; ++i) {
            double xv = xrow[w][i];
            pb += xv * wb[i * D + j];
            pc += xv * wc[i * D + j];
        }
        const int g = (int)(n >> 12);
        Pb[n * D + j] = (float)(pb - qb[g * D + j]);
        Pc[n * D + j] = (float)(pc - qc[g * D + j]);
        __syncthreads();
    }
}

// ---- edge scorer, CSR order: all-f32 tile GEMM + sample; near-threshold
// ---- edges (|score+g| < FIXTH) deferred to k_fix for exact f64 decision.
// LDS: A f32 [64][68] 17KB (reused as f32 sred), W f32 [64][68] 17KB.
template <int LAYER>
__global__ __launch_bounds__(256, 4) void k_edge(const float* __restrict__ xsrc,
                                                 const int* __restrict__ src_csr,
                                                 const int* __restrict__ dst_csr,
                                                 const int* __restrict__ eord,
                                                 const float* __restrict__ ewin,
                                                 double* __restrict__ ew_csr,
                                                 const float* __restrict__ unoise,
                                                 const float* __restrict__ epW1,
                                                 const float* __restrict__ epb1,
                                                 const float* __restrict__ epW2,
                                                 const float* __restrict__ epb2,
                                                 const float* __restrict__ alphap,
                                                 const float* __restrict__ Pb32,
                                                 const float* __restrict__ Pc32,
                                                 int* __restrict__ flagcnt,
                                                 int* __restrict__ flaglist,
                                                 float* __restrict__ out) {
    const int t = threadIdx.x;
    const int tx = t & 15, ty = t >> 4;

    __shared__ __align__(16) float ldsA[64 * 68];  // |dx| [dim][slot]
    __shared__ float ldsW[64 * 68];                // W1a [k][j]

    for (int idx = t; idx < D * D; idx += 256) {
        int k = idx >> 6, j = idx & 63;
        ldsW[k * 68 + j] = epW1[idx];
    }
    float b1f[4], w2f[4];
#pragma unroll
    for (int c = 0; c < 4; ++c) {
        b1f[c] = epb1[4 * tx + c];
        w2f[c] = epW2[4 * tx + c];
    }
    const float b2v = epb2[0];
    const float alpha = alphap[0];
    __syncthreads();

    const int eloc = t >> 2, q = t & 3;

    for (int tile = blockIdx.x; tile < NTILE; tile += gridDim.x) {
        const int base = tile * 64;

        // ---- stage |x_d - x_s| (f32, transposed). d-rows run-repeat (L1). --
        {
            const int pos = base + eloc;
            const int s = src_csr[pos], d = dst_csr[pos];
            const float* rs = xsrc + (size_t)s * D + q * 16;
            const float* rd = xsrc + (size_t)d * D + q * 16;
#pragma unroll
            for (int c = 0; c < 4; ++c) {
                const float4 fd = *(const float4*)(rd + 4 * c);
                const float4 fs = *(const float4*)(rs + 4 * c);
                const int dim = q * 16 + 4 * c;
                ldsA[(dim + 0) * 68 + eloc] = fabsf(fd.x - fs.x);
                ldsA[(dim + 1) * 68 + eloc] = fabsf(fd.y - fs.y);
                ldsA[(dim + 2) * 68 + eloc] = fabsf(fd.z - fs.z);
                ldsA[(dim + 3) * 68 + eloc] = fabsf(fd.w - fs.w);
            }
        }
        __syncthreads();

        // ---- 64x64x64 GEMM: f32 inputs, f32 accumulate, 4x4 per thread ----
        float acc[4][4];
#pragma unroll
        for (int r = 0; r < 4; ++r)
#pragma unroll
            for (int c = 0; c < 4; ++c) acc[r][c] = 0.0f;

#pragma unroll 4
        for (int k = 0; k < 64; ++k) {
            const float4 af = *(const float4*)&ldsA[k * 68 + 4 * ty];
            const float4 wf = *(const float4*)&ldsW[k * 68 + 4 * tx];
            const float av[4] = {af.x, af.y, af.z, af.w};
            const float wv[4] = {wf.x, wf.y, wf.z, wf.w};
#pragma unroll
            for (int r = 0; r < 4; ++r)
#pragma unroll
                for (int c = 0; c < 4; ++c) acc[r][c] += av[r] * wv[c];
        }
        __syncthreads();  // A dead -> reuse as f32 sred

        float* sred = ldsA;
        // ---- epilogue: + P' terms, +b1, relu, * w2, partial sums ----
#pragma unroll
        for (int r = 0; r < 4; ++r) {
            const int pos = base + 4 * ty + r;
            const int s = src_csr[pos], d = dst_csr[pos];
            const float4 pb = *(const float4*)(Pb32 + (size_t)d * D + 4 * tx);
            const float4 pc = *(const float4*)(Pc32 + (size_t)s * D + 4 * tx);
            float part = 0.0f;
            float h;
            h = acc[r][0] + pb.x + pc.x + b1f[0];
            if (h > 0.0f) part += h * w2f[0];
            h = acc[r][1] + pb.y + pc.y + b1f[1];
            if (h > 0.0f) part += h * w2f[1];
            h = acc[r][2] + pb.z + pc.z + b1f[2];
            if (h > 0.0f) part += h * w2f[2];
            h = acc[r][3] + pb.w + pc.w + b1f[3];
            if (h > 0.0f) part += h * w2f[3];
            sred[(4 * ty + r) * 17 + tx] = part;
        }
        __syncthreads();

        // ---- score reduce + RelaxedBernoulli sample (one lane per slot) ----
        if (t < 64) {
            float sc_ = b2v;
#pragma unroll
            for (int i = 0; i < 16; ++i) sc_ += sred[t * 17 + i];
            const int pos = base + t;
            const int e = eord[pos];
            const float u = unoise[(size_t)LAYER * NE + e];
            const float gn = logf(u) - log1pf(-u);
            const float mar = sc_ + gn;  // decision margin; samp == (mar > 0)
            bool deferred = false;
            if (fabsf(mar) < FIXTH) {
                int slot = atomicAdd(flagcnt, 1);
                if (slot < FLAGCAP) {
                    flaglist[slot] = pos;
                    deferred = true;  // k_fix decides + writes this edge
                }
            }
            if (!deferred) {
                const float pre = 1.0f / (1.0f + expf(-sc_));
                const bool samp = mar > 0.0f;
                const float ewo = (LAYER == 0) ? ewin[e] : (float)ew_csr[pos];
                const float ewn = samp ? alpha * ewo + (1.0f - alpha) * pre : 0.0f;
                ew_csr[pos] = (double)ewn;
                if (LAYER == NL - 1) {
                    out[OUT_EW + (size_t)e] = ewn;
                    out[OUT_PA + (size_t)e] = pre;
                }
            }
        }
        __syncthreads();
    }
}

// ---- exact f64 re-decision for near-threshold edges (one wave per edge) ----
template <int LAYER>
__global__ __launch_bounds__(256) void k_fix(const float* __restrict__ xsrc,
                                             const int* __restrict__ src_csr,
                                             const int* __restrict__ dst_csr,
                                             const int* __restrict__ eord,
                                             const float* __restrict__ ewin,
                                             double* __restrict__ ew_csr,
                                             const float* __restrict__ unoise,
                                             const float* __restrict__ epW1,
                                             const float* __restrict__ epb1,
                                             const float* __restrict__ epW2,
                                             const float* __restrict__ epb2,
                                             const float* __restrict__ alphap,
                                             const float* __restrict__ Pb32,
                                             const float* __restrict__ Pc32,
                                             const int* __restrict__ flagcnt,
                                             const int* __restrict__ flaglist,
                                             float* __restrict__ out) {
    const int n = min(flagcnt[0], FLAGCAP);
    __shared__ float dxs[4][D];
    const int w = threadIdx.x >> 6, lane = threadIdx.x & 63;
    const int nw = gridDim.x * 4;
    for (int i = blockIdx.x * 4 + w; i < n; i += nw) {
        const int pos = flaglist[i];
        const int s = src_csr[pos], d = dst_csr[pos];
        // |dx| from the same f32 inputs the main kernel staged
        dxs[w][lane] = fabsf(xsrc[(size_t)d * D + lane] - xsrc[(size_t)s * D + lane]);
        // wave-internal broadcast (same-wave DS in-order)
        double h = 0.0;
#pragma unroll
        for (int k = 0; k < D; ++k) h += (double)dxs[w][k] * (double)epW1[k * D + lane];
        h += (double)Pb32[(size_t)d * D + lane] + (double)Pc32[(size_t)s * D + lane] +
             (double)epb1[lane];
        double part = (h > 0.0) ? h * (double)epW2[lane] : 0.0;
#pragma unroll
        for (int off = 32; off; off >>= 1) part += __shfl_xor(part, off);
        if (lane == 0) {
            const double sc_ = part + (double)epb2[0];
            const int e = eord[pos];
            const double u = (double)unoise[(size_t)LAYER * NE + e];
            const double gn = log(u) - log1p(-u);
            const double pre = 1.0 / (1.0 + exp(-sc_));
            const bool samp = (sc_ + gn) > 0.0;
            const double ewo = (LAYER == 0) ? (double)ewin[e] : ew_csr[pos];
            const double alpha = (double)alphap[0];
            const double ewn = samp ? alpha * ewo + (1.0 - alpha) * pre : 0.0;
            ew_csr[pos] = ewn;
            if (LAYER == NL - 1) {
                out[OUT_EW + (size_t)e] = (float)ewn;
                out[OUT_PA + (size_t)e] = (float)pre;
            }
        }
    }
}

// ---- node update: CSR gather-aggregate + GIN mlp + relu + BN partials ----
// xsrc: f32 node rows (xin for layer 0, x32 mirror for layer 1). Gathers f32,
// accumulate + matvec f64. Masked 16-wide gather batch: 16 loads in flight.
template <int LAYER>
__global__ __launch_bounds__(256, 4) void k_nodeup(const float* __restrict__ xsrc,
                                                   const double* __restrict__ ew_csr,
                                                   const int* __restrict__ src_csr,
                                                   const int* __restrict__ rowptr,
                                                   const float* __restrict__ ginW,
                                                   const float* __restrict__ ginB,
                                                   double* __restrict__ xh,
                                                   double* __restrict__ bnacc) {
    __shared__ float wg[D * D];
    __shared__ double rowbuf[4][D];
    const int t = threadIdx.x, w = t >> 6, j = t & 63;
    for (int idx = t; idx < D * D; idx += 256) wg[idx] = ginW[LAYER * D * D + idx];
    const double bj = (double)ginB[LAYER * D + j];
    __syncthreads();
    double s1 = 0.0, s2 = 0.0;
    const int nwaves = gridDim.x * 4;
    for (int n = blockIdx.x * 4 + w; n < NN; n += nwaves) {
        const int rs = rowptr[n], re = rowptr[n + 1];
        const int cnt = re - rs;
        double acc = (double)xsrc[(size_t)n * D + j];
        // ---- first up-to-16 edges: all loads batched for MLP-latency hiding
        {
            int se[16];
            float we[16];
            float xr[16];
#pragma unroll
            for (int e = 0; e < 16; ++e) {
                const bool v = e < cnt;
                se[e] = v ? src_csr[rs + e] : n;
            }
#pragma unroll
            for (int e = 0; e < 16; ++e) {
                const bool v = e < cnt;
                we[e] = v ? (float)ew_csr[rs + (v ? e : 0)] : 0.0f;
            }
#pragma unroll
            for (int e = 0; e < 16; ++e) xr[e] = xsrc[(size_t)se[e] * D + j];
#pragma unroll
            for (int e = 0; e < 16; ++e) acc += (double)we[e] * (double)xr[e];
        }
        // ---- tail: edges beyond 16 (Poisson-16 => ~half the nodes) ----
        int k = rs + 16;
        for (; k + 4 <= re; k += 4) {
            const float w0 = (float)ew_csr[k], w1 = (float)ew_csr[k + 1];
            const float w2 = (float)ew_csr[k + 2], w3 = (float)ew_csr[k + 3];
            const int s0 = src_csr[k], s1_ = src_csr[k + 1];
            const int s2_ = src_csr[k + 2], s3 = src_csr[k + 3];
            const float x0 = xsrc[(size_t)s0 * D + j], x1 = xsrc[(size_t)s1_ * D + j];
            const float x2 = xsrc[(size_t)s2_ * D + j], x3 = xsrc[(size_t)s3 * D + j];
            acc += (double)w0 * (double)x0;
            acc += (double)w1 * (double)x1;
            acc += (double)w2 * (double)x2;
            acc += (double)w3 * (double)x3;
        }
        for (; k < re; ++k)
            acc += (double)(float)ew_csr[k] * (double)xsrc[(size_t)src_csr[k] * D + j];

        rowbuf[w][j] = acc;  // wave-internal broadcast (same-wave DS in-order)
        double h = bj;
#pragma unroll
        for (int i = 0; i < D; ++i) h += rowbuf[w][i] * (double)wg[i * D + j];
        h = h > 0.0 ? h : 0.0;
        xh[(size_t)n * D + j] = h;
        s1 += h;
        s2 += h * h;
    }
    atomAdd64(&bnacc[j], s1);
    atomAdd64(&bnacc[64 + j], s2);
}

// ---- BN finalize ----
__global__ __launch_bounds__(64) void k_bnfin(int layer, const float* __restrict__ gamma,
                                              const float* __restrict__ beta,
                                              const double* __restrict__ bnacc,
                                              double* __restrict__ bnsc) {
    int j = threadIdx.x;
    double mu = bnacc[j] * (1.0 / NN);
    double var = bnacc[64 + j] * (1.0 / NN) - mu * mu;
    double sc = (double)gamma[layer * D + j] / sqrt(var + 1e-5);
    bnsc[j] = sc;
    bnsc[64 + j] = (double)beta[layer * D + j] - mu * sc;
}

// ---- BN apply -> x64 (+x32 mirror for edge/nodeup staging; final out) ----
template <int LAYER>
__global__ __launch_bounds__(256) void k_bnapply(const double* __restrict__ bnsc,
                                                 const double* __restrict__ xh,
                                                 double* __restrict__ x64,
                                                 float* __restrict__ x32,
                                                 float* __restrict__ out) {
    size_t stride = (size_t)gridDim.x * 256;
    for (size_t i = (size_t)blockIdx.x * 256 + threadIdx.x; i < (size_t)NN * D; i += stride) {
        int j = (int)(i & 63);
        double v = bnsc[j] * xh[i] + bnsc[64 + j];
        x64[i] = v;
        if (LAYER == 0) x32[i] = (float)v;
        if (LAYER == NL - 1) out[OUT_X + i] = (float)v;
    }
}

// ---- attention pooling, parallelized: 4 kernels ----
__global__ __launch_bounds__(256) void k_att1(const double* __restrict__ x64,
                                              const double* __restrict__ c64,
                                              double* __restrict__ sc,
                                              double* __restrict__ bmax) {
    const int blk = blockIdx.x, t = threadIdx.x, w = t >> 6, lane = t & 63;
    const int g = blk >> 6;
    __shared__ double wmax[4];
    const double cj = c64[g * D + lane];
    double locmax = -1e300;
    for (int m = 0; m < 16; ++m) {
        const int n = blk * 64 + w * 16 + m;
        double v = x64[(size_t)n * D + lane] * cj;
#pragma unroll
        for (int off = 32; off; off >>= 1) v += __shfl_xor(v, off);
        if (lane == 0) sc[n] = v;
        locmax = fmax(locmax, v);
    }
    if (lane == 0) wmax[w] = locmax;
    __syncthreads();
    if (t == 0) bmax[blk] = fmax(fmax(wmax[0], wmax[1]), fmax(wmax[2], wmax[3]));
}

__global__ __launch_bounds__(64) void k_att2(const double* __restrict__ bmax,
                                             double* __restrict__ mxg,
                                             double* __restrict__ num,
                                             double* __restrict__ den) {
    const int g = blockIdx.x, t = threadIdx.x;
    double m = bmax[g * 64 + t];
#pragma unroll
    for (int off = 32; off; off >>= 1) m = fmax(m, __shfl_xor(m, off));
    if (t == 0) {
        mxg[g] = m;
        den[g] = 0.0;
    }
    num[g * D + t] = 0.0;
}

__global__ __launch_bounds__(256) void k_att3(const double* __restrict__ x64,
                                              const double* __restrict__ sc,
                                              const double* __restrict__ mxg,
                                              double* __restrict__ num,
                                              double* __restrict__ den) {
    const int blk = blockIdx.x, t = threadIdx.x, w = t >> 6, lane = t & 63;
    const int g = blk >> 6;
    __shared__ double cp[4][D];
    __shared__ double wes[4];
    const double mx = mxg[g];
    double accj = 0.0, esum = 0.0;
    for (int m = 0; m < 16; ++m) {
        const int n = blk * 64 + w * 16 + m;
        const double e = exp(sc[n] - mx);
        accj += e * x64[(size_t)n * D + lane];
        esum += e;
    }
    cp[w][lane] = accj;
    if (lane == 0) wes[w] = esum;
    __syncthreads();
    if (t < D) {
        atomAdd64(&num[g * D + t], cp[0][t] + cp[1][t] + cp[2][t] + cp[3][t]);
        if (t == 0) atomAdd64(&den[g], wes[0] + wes[1] + wes[2] + wes[3]);
    }
}

__global__ __launch_bounds__(64) void k_att4(const double* __restrict__ num,
                                             const double* __restrict__ den,
                                             double* __restrict__ c64) {
    const int g = blockIdx.x, t = threadIdx.x;
    c64[g * D + t] = num[g * D + t] / den[g];
}

// ---- head: relu(x@W1+b1)@W2+b2 for all nodes + 16 centroid rows (f32) ----
__global__ __launch_bounds__(256) void k_head(const double* __restrict__ x64,
                                              const double* __restrict__ c64,
                                              const float* __restrict__ hW1,
                                              const float* __restrict__ hb1,
                                              const float* __restrict__ hW2,
                                              const float* __restrict__ hb2,
                                              float* __restrict__ out) {
    __shared__ float w1[D * D];
    __shared__ float w2[D * D];
    __shared__ float xr[4][D];
    __shared__ float hr[4][D];
    int tid = threadIdx.x, w = tid >> 6, j = tid & 63;
    for (int idx = tid; idx < D * D; idx += 256) {
        w1[idx] = hW1[idx];
        w2[idx] = hW2[idx];
    }
    const float b1j = hb1[j];
    const float b2j = hb2[j];
    __syncthreads();
    const int ROWS = NN + BSZ;
    for (int grp = blockIdx.x; grp * 4 < ROWS; grp += gridDim.x) {
        int r = grp * 4 + w;
        bool valid = r < ROWS;
        float xv = 0.f;
        if (valid)
            xv = (r < NN) ? (float)x64[(size_t)r * D + j] : (float)c64[(size_t)(r - NN) * D + j];
        xr[w][j] = xv;
        __syncthreads();
        if (valid) {
            float h = b1j;
#pragma unroll
            for (int i = 0; i < D; ++i) h += xr[w][i] * w1[i * D + j];
            hr[w][j] = h > 0.f ? h : 0.f;
        }
        __syncthreads();
        if (valid) {
            float o = b2j;
#pragma unroll
            for (int i = 0; i < D; ++i) o += hr[w][i] * w2[i * D + j];
            if (r < NN) {
                out[OUT_XL + (size_t)r * D + j] = o;
            } else {
                size_t cr = (size_t)(r - NN) * D + j;
                out[OUT_CL + cr] = o;
                out[OUT_C + cr] = (float)c64[cr];
            }
        }
        __syncthreads();
    }
}

extern "C" void kernel_launch(void* const* d_in, const int* in_sizes, int n_in,
                              void* d_out, int out_size, void* d_ws, size_t ws_size,
                              hipStream_t stream) {
    const float* xin    = (const float*)d_in[0];
    const int*   ei     = (const int*)d_in[1];
    const float* ewin   = (const float*)d_in[2];
    const float* unoise = (const float*)d_in[5];
    const float* epW1   = (const float*)d_in[6];
    const float* epb1   = (const float*)d_in[7];
    const float* epW2   = (const float*)d_in[8];
    const float* epb2   = (const float*)d_in[9];
    const float* alphap = (const float*)d_in[10];
    const float* ginW   = (const float*)d_in[11];
    const float* ginB   = (const float*)d_in[12];
    const float* bng    = (const float*)d_in[13];
    const float* bnb    = (const float*)d_in[14];
    const float* hW1    = (const float*)d_in[15];
    const float* hb1    = (const float*)d_in[16];
    const float* hW2    = (const float*)d_in[17];
    const float* hb2    = (const float*)d_in[18];
    float* out = (float*)d_out;
    const int* esrc = ei;
    const int* edst = ei + NE;

    char* ws = (char*)d_ws;
    const size_t SZ = (size_t)NN * D * sizeof(double);  // 33554432
    double* x64  = (double*)(ws);
    // Pb/Pc (k_P->k_edge) and xh (k_nodeup->k_bnapply): disjoint live ranges.
    float*  Pb32 = (float*)(ws + SZ);
    float*  Pc32 = (float*)(ws + SZ + SZ / 2);
    double* xh   = (double*)(ws + SZ);
    float*  x32  = (float*)(ws + 2 * SZ);                       // NN*D*4 = 16MB
    double* ew_csr = (double*)(ws + 2 * SZ + SZ / 2);           // NE*8 = 8MB
    double* sc   = (double*)(ws + 2 * SZ + SZ / 2 + (size_t)NE * 8);  // NN*8
    char*   p    = ws + 2 * SZ + SZ / 2 + (size_t)NE * 8 + (size_t)NN * 8;
    double* c64  = (double*)p;          p += BSZ * D * 8;
    double* qb   = (double*)p;          p += BSZ * D * 8;
    double* qc   = (double*)p;          p += BSZ * D * 8;
    double* bnacc = (double*)p;         p += 128 * 8;
    double* bnsc  = (double*)p;         p += 128 * 8;
    double* bmax  = (double*)p;         p += 1024 * 8;
    double* mxg   = (double*)p;         p += 16 * 8;
    double* num   = (double*)p;         p += BSZ * D * 8;
    double* den   = (double*)p;         p += 16 * 8;
    // CSR
    int* cnt     = (int*)p;             p += (size_t)NN * 4;
    int* rowptr  = (int*)p;             p += (size_t)(NN + 1) * 4 + 4;
    int* cursor  = (int*)p;             p += (size_t)NN * 4;
    int* bsum    = (int*)p;             p += 256 * 4;
    int* eord    = (int*)p;             p += (size_t)NE * 4;
    int* src_csr = (int*)p;             p += (size_t)NE * 4;
    int* dst_csr = (int*)p;             p += (size_t)NE * 4;
    // near-threshold fixup list
    int* flagcnt  = (int*)p;            p += 8;
    int* flaglist = (int*)p;            p += (size_t)FLAGCAP * 4;

    // ---- CSR build (dst static) ----
    hipMemsetAsync(cnt, 0, (size_t)NN * 4, stream);
    k_deg<<<1024, 256, 0, stream>>>(edst, cnt);
    k_scan1<<<256, 256, 0, stream>>>(cnt, rowptr, bsum);
    k_scan2<<<1, 256, 0, stream>>>(bsum);
    k_scan3<<<256, 256, 0, stream>>>(bsum, rowptr, cursor);
    k_fill<<<1024, 256, 0, stream>>>(esrc, edst, cursor, eord, src_csr, dst_csr);

    k_centroid0<<<BSZ, 256, 0, stream>>>(xin, c64);

    // ---------------- layer 0 ----------------
    k_qbc<<<4, 256, 0, stream>>>(c64, epW1, qb, qc);
    k_P<0><<<1024, 256, 0, stream>>>(xin, x64, epW1, qb, qc, Pb32, Pc32, bnacc);
    hipMemsetAsync(flagcnt, 0, 4, stream);
    k_edge<0><<<2048, 256, 0, stream>>>(xin, src_csr, dst_csr, eord, ewin, ew_csr, unoise,
                                        epW1, epb1, epW2, epb2, alphap, Pb32, Pc32,
                                        flagcnt, flaglist, out);
    k_fix<0><<<64, 256, 0, stream>>>(xin, src_csr, dst_csr, eord, ewin, ew_csr, unoise,
                                     epW1, epb1, epW2, epb2, alphap, Pb32, Pc32,
                                     flagcnt, flaglist, out);
    k_nodeup<0><<<2048, 256, 0, stream>>>(xin, ew_csr, src_csr, rowptr, ginW, ginB,
                                          xh, bnacc);
    k_bnfin<<<1, 64, 0, stream>>>(0, bng, bnb, bnacc, bnsc);
    k_bnapply<0><<<2048, 256, 0, stream>>>(bnsc, xh, x64, x32, out);
    k_att1<<<1024, 256, 0, stream>>>(x64, c64, sc, bmax);
    k_att2<<<16, 64, 0, stream>>>(bmax, mxg, num, den);
    k_att3<<<1024, 256, 0, stream>>>(x64, sc, mxg, num, den);
    k_att4<<<16, 64, 0, stream>>>(num, den, c64);

    // ---------------- layer 1 ----------------
    k_qbc<<<4, 256, 0, stream>>>(c64, epW1, qb, qc);
    k_P<1><<<1024, 256, 0, stream>>>(xin, x64, epW1, qb, qc, Pb32, Pc32, bnacc);
    hipMemsetAsync(flagcnt, 0, 4, stream);
    k_edge<1><<<2048, 256, 0, stream>>>(x32, src_csr, dst_csr, eord, ewin, ew_csr, unoise,
                                        epW1, epb1, epW2, epb2, alphap, Pb32, Pc32,
                                        flagcnt, flaglist, out);
    k_fix<1><<<64, 256, 0, stream>>>(x32, src_csr, dst_csr, eord, ewin, ew_csr, unoise,
                                     epW1, epb1, epW2, epb2, alphap, Pb32, Pc32,
                                     flagcnt, flaglist, out);
    k_nodeup<1><<<2048, 256, 0, stream>>>(x32, ew_csr, src_csr, rowptr, ginW, ginB,
                                          xh, bnacc);
    k_bnfin<<<1, 64, 0, stream>>>(1, bng, bnb, bnacc, bnsc);
    k_bnapply<1><<<2048, 256, 0, stream>>>(bnsc, xh, x64, x32, out);
    k_att1<<<1024, 256, 0, stream>>>(x64, c64, sc, bmax);
    k_att2<<<16, 64, 0, stream>>>(bmax, mxg, num, den);
    k_att3<<<1024, 256, 0, stream>>>(x64, sc, mxg, num, den);
    k_att4<<<16, 64, 0, stream>>>(num, den, c64);

    // ---------------- heads + centroid output ----------------
    k_head<<<2048, 256, 0, stream>>>(x64, c64, hW1, hb1, hW2, hb2, out);
}

// Round 3
// 1260.942 us; speedup vs baseline: 1.3031x; 1.3031x over previous
//
#include <hip/hip_runtime.h>
#include <hip/hip_bf16.h>

// GraphCAD forward on MI355X. All float I/O is f32.
// R9->R10 post-mortem: R9's 16-wide gather batch (3x16-entry arrays +
// __launch_bounds__(256,4)) made the compiler allocate 64 VGPRs and SPILL the
// batch to scratch: WRITE_SIZE 41->213MB, FETCH 258->836MB. R10 keeps R8's
// no-array scalar structure and gets MLP differently: each wave processes a
// node PAIR (na, nb=na+8192) with interleaved 4-wide groups -> 8 named-
// register gathers in flight, wave-uniform control flow. Gathers read f32
// rows (xin / x32 mirror); acc + GIN matvec stay f64. ew_csr stored f32
// (values are f32-born in k_edge; k_fix's ~50 edges round at 1e-8 on a
// continuous path; layer-1 k_edge already rounded via (float) before).

#define D 64
#define BSZ 16
#define NPG 4096
#define NN (BSZ * NPG)   // 65536 nodes
#define NE (NN * 16)     // 1048576 edges
#define NL 2
#define NTILE (NE / 64)  // 16384

#define FIXTH 2e-3f
#define FLAGCAP 65536

// output layout (elements, f32)
#define OUT_X  0u
#define OUT_EW 4194304u
#define OUT_C  5242880u
#define OUT_XL 5243904u
#define OUT_CL 9438208u
#define OUT_PA 9439232u

__device__ __forceinline__ void atomAdd64(double* p, double v) { unsafeAtomicAdd(p, v); }

// ================= CSR build (dst is a static input; rebuilt per call) ======
__global__ __launch_bounds__(256) void k_deg(const int* __restrict__ edst,
                                             int* __restrict__ cnt) {
    int stride = gridDim.x * 256;
    for (int e = blockIdx.x * 256 + threadIdx.x; e < NE; e += stride)
        atomicAdd(&cnt[edst[e]], 1);
}

__global__ __launch_bounds__(256) void k_scan1(const int* __restrict__ cnt,
                                               int* __restrict__ rowptr,
                                               int* __restrict__ bsum) {
    __shared__ int sd[256];
    const int b = blockIdx.x, t = threadIdx.x;
    const int v = cnt[b * 256 + t];
    sd[t] = v;
    __syncthreads();
    for (int off = 1; off < 256; off <<= 1) {
        int tmp = (t >= off) ? sd[t - off] : 0;
        __syncthreads();
        sd[t] += tmp;
        __syncthreads();
    }
    rowptr[b * 256 + t] = sd[t] - v;  // exclusive
    if (t == 255) bsum[b] = sd[255];
}

__global__ __launch_bounds__(256) void k_scan2(int* __restrict__ bsum) {
    __shared__ int sd[256];
    const int t = threadIdx.x;
    const int v = bsum[t];
    sd[t] = v;
    __syncthreads();
    for (int off = 1; off < 256; off <<= 1) {
        int tmp = (t >= off) ? sd[t - off] : 0;
        __syncthreads();
        sd[t] += tmp;
        __syncthreads();
    }
    bsum[t] = sd[t] - v;  // exclusive
}

__global__ __launch_bounds__(256) void k_scan3(const int* __restrict__ bsum,
                                               int* __restrict__ rowptr,
                                               int* __restrict__ cursor) {
    const int i = blockIdx.x * 256 + threadIdx.x;
    const int r = rowptr[i] + bsum[blockIdx.x];
    rowptr[i] = r;
    cursor[i] = r;
    if (i == 0) rowptr[NN] = NE;
}

// fill CSR: slot -> original edge (eord), src (src_csr), dst (dst_csr).
__global__ __launch_bounds__(256) void k_fill(const int* __restrict__ esrc,
                                              const int* __restrict__ edst,
                                              int* __restrict__ cursor,
                                              int* __restrict__ eord,
                                              int* __restrict__ src_csr,
                                              int* __restrict__ dst_csr) {
    int stride = gridDim.x * 256;
    for (int e = blockIdx.x * 256 + threadIdx.x; e < NE; e += stride) {
        const int d = edst[e];
        int pos = atomicAdd(&cursor[d], 1);
        eord[pos] = e;
        src_csr[pos] = esrc[e];
        dst_csr[pos] = d;
    }
}

// ---- initial centroid: per-graph mean of x (f32 in, f64 out) ----
__global__ __launch_bounds__(256) void k_centroid0(const float* __restrict__ xin,
                                                   double* __restrict__ c64) {
    int g = blockIdx.x, tid = threadIdx.x;
    int r = tid >> 6, f = tid & 63;
    __shared__ double cr[4][D];
    double s = 0.0;
    for (int k = 0; k < NPG / 4; ++k) {
        size_t n = (size_t)g * NPG + (size_t)(4 * k + r);
        s += (double)xin[n * D + f];
    }
    cr[r][f] = s;
    __syncthreads();
    if (tid < D)
        c64[g * D + tid] = (cr[0][tid] + cr[1][tid] + cr[2][tid] + cr[3][tid]) * (1.0 / NPG);
}

// ---- qb = c @ W1b, qc = c @ W1c (per graph, f64) ----
__global__ __launch_bounds__(256) void k_qbc(const double* __restrict__ c64,
                                             const float* __restrict__ epW1,
                                             double* __restrict__ qb, double* __restrict__ qc) {
    int gj = blockIdx.x * 256 + threadIdx.x;
    if (gj >= BSZ * D) return;
    int g = gj >> 6, j = gj & 63;
    double sb = 0.0, sc = 0.0;
#pragma unroll
    for (int i = 0; i < D; ++i) {
        double cv = c64[g * D + i];
        sb += cv * (double)epW1[(D + i) * D + j];
        sc += cv * (double)epW1[(2 * D + i) * D + j];
    }
    qb[gj] = sb;
    qc[gj] = sc;
}

// ---- P'_b = x@W1b - qb[g], P'_c = x@W1c - qc[g]; f64 compute, f32 store ----
template <int LAYER>
__global__ __launch_bounds__(256) void k_P(const float* __restrict__ xin,
                                           const double* __restrict__ x64,
                                           const float* __restrict__ epW1,
                                           const double* __restrict__ qb,
                                           const double* __restrict__ qc,
                                           float* __restrict__ Pb, float* __restrict__ Pc,
                                           double* __restrict__ bnacc) {
    if (blockIdx.x == 0 && threadIdx.x < 128) bnacc[threadIdx.x] = 0.0;
    __shared__ double wb[D * D];
    __shared__ double wc[D * D];
    __shared__ double xrow[4][D];
    int tid = threadIdx.x, w = tid >> 6, j = tid & 63;
    for (int idx = tid; idx < D * D; idx += 256) {
        int i = idx >> 6, c = idx & 63;
        wb[idx] = (double)epW1[(D + i) * D + c];
        wc[idx] = (double)epW1[(2 * D + i) * D + c];
    }
    __syncthreads();
    for (int grp = blockIdx.x; grp < NN / 4; grp += gridDim.x) {
        size_t n = (size_t)grp * 4 + w;
        xrow[w][j] = (LAYER == 0) ? (double)xin[n * D + j] : x64[n * D + j];
        __syncthreads();
        double pb = 0.0, pc = 0.0;
#pragma unroll
        for (int i = 0; i < D; ++i) {
            double xv = xrow[w][i];
            pb += xv * wb[i * D + j];
            pc += xv * wc[i * D + j];
        }
        const int g = (int)(n >> 12);
        Pb[n * D + j] = (float)(pb - qb[g * D + j]);
        Pc[n * D + j] = (float)(pc - qc[g * D + j]);
        __syncthreads();
    }
}

// ---- edge scorer, CSR order: all-f32 tile GEMM + sample; near-threshold
// ---- edges (|score+g| < FIXTH) deferred to k_fix for exact f64 decision.
// LDS: A f32 [64][68] 17KB (reused as f32 sred), W f32 [64][68] 17KB.
template <int LAYER>
__global__ __launch_bounds__(256, 4) void k_edge(const float* __restrict__ xsrc,
                                                 const int* __restrict__ src_csr,
                                                 const int* __restrict__ dst_csr,
                                                 const int* __restrict__ eord,
                                                 const float* __restrict__ ewin,
                                                 float* __restrict__ ew_csr,
                                                 const float* __restrict__ unoise,
                                                 const float* __restrict__ epW1,
                                                 const float* __restrict__ epb1,
                                                 const float* __restrict__ epW2,
                                                 const float* __restrict__ epb2,
                                                 const float* __restrict__ alphap,
                                                 const float* __restrict__ Pb32,
                                                 const float* __restrict__ Pc32,
                                                 int* __restrict__ flagcnt,
                                                 int* __restrict__ flaglist,
                                                 float* __restrict__ out) {
    const int t = threadIdx.x;
    const int tx = t & 15, ty = t >> 4;

    __shared__ __align__(16) float ldsA[64 * 68];  // |dx| [dim][slot]
    __shared__ float ldsW[64 * 68];                // W1a [k][j]

    for (int idx = t; idx < D * D; idx += 256) {
        int k = idx >> 6, j = idx & 63;
        ldsW[k * 68 + j] = epW1[idx];
    }
    float b1f[4], w2f[4];
#pragma unroll
    for (int c = 0; c < 4; ++c) {
        b1f[c] = epb1[4 * tx + c];
        w2f[c] = epW2[4 * tx + c];
    }
    const float b2v = epb2[0];
    const float alpha = alphap[0];
    __syncthreads();

    const int eloc = t >> 2, q = t & 3;

    for (int tile = blockIdx.x; tile < NTILE; tile += gridDim.x) {
        const int base = tile * 64;

        // ---- stage |x_d - x_s| (f32, transposed). d-rows run-repeat (L1). --
        {
            const int pos = base + eloc;
            const int s = src_csr[pos], d = dst_csr[pos];
            const float* rs = xsrc + (size_t)s * D + q * 16;
            const float* rd = xsrc + (size_t)d * D + q * 16;
#pragma unroll
            for (int c = 0; c < 4; ++c) {
                const float4 fd = *(const float4*)(rd + 4 * c);
                const float4 fs = *(const float4*)(rs + 4 * c);
                const int dim = q * 16 + 4 * c;
                ldsA[(dim + 0) * 68 + eloc] = fabsf(fd.x - fs.x);
                ldsA[(dim + 1) * 68 + eloc] = fabsf(fd.y - fs.y);
                ldsA[(dim + 2) * 68 + eloc] = fabsf(fd.z - fs.z);
                ldsA[(dim + 3) * 68 + eloc] = fabsf(fd.w - fs.w);
            }
        }
        __syncthreads();

        // ---- 64x64x64 GEMM: f32 inputs, f32 accumulate, 4x4 per thread ----
        float acc[4][4];
#pragma unroll
        for (int r = 0; r < 4; ++r)
#pragma unroll
            for (int c = 0; c < 4; ++c) acc[r][c] = 0.0f;

#pragma unroll 4
        for (int k = 0; k < 64; ++k) {
            const float4 af = *(const float4*)&ldsA[k * 68 + 4 * ty];
            const float4 wf = *(const float4*)&ldsW[k * 68 + 4 * tx];
            const float av[4] = {af.x, af.y, af.z, af.w};
            const float wv[4] = {wf.x, wf.y, wf.z, wf.w};
#pragma unroll
            for (int r = 0; r < 4; ++r)
#pragma unroll
                for (int c = 0; c < 4; ++c) acc[r][c] += av[r] * wv[c];
        }
        __syncthreads();  // A dead -> reuse as f32 sred

        float* sred = ldsA;
        // ---- epilogue: + P' terms, +b1, relu, * w2, partial sums ----
#pragma unroll
        for (int r = 0; r < 4; ++r) {
            const int pos = base + 4 * ty + r;
            const int s = src_csr[pos], d = dst_csr[pos];
            const float4 pb = *(const float4*)(Pb32 + (size_t)d * D + 4 * tx);
            const float4 pc = *(const float4*)(Pc32 + (size_t)s * D + 4 * tx);
            float part = 0.0f;
            float h;
            h = acc[r][0] + pb.x + pc.x + b1f[0];
            if (h > 0.0f) part += h * w2f[0];
            h = acc[r][1] + pb.y + pc.y + b1f[1];
            if (h > 0.0f) part += h * w2f[1];
            h = acc[r][2] + pb.z + pc.z + b1f[2];
            if (h > 0.0f) part += h * w2f[2];
            h = acc[r][3] + pb.w + pc.w + b1f[3];
            if (h > 0.0f) part += h * w2f[3];
            sred[(4 * ty + r) * 17 + tx] = part;
        }
        __syncthreads();

        // ---- score reduce + RelaxedBernoulli sample (one lane per slot) ----
        if (t < 64) {
            float sc_ = b2v;
#pragma unroll
            for (int i = 0; i < 16; ++i) sc_ += sred[t * 17 + i];
            const int pos = base + t;
            const int e = eord[pos];
            const float u = unoise[(size_t)LAYER * NE + e];
            const float gn = logf(u) - log1pf(-u);
            const float mar = sc_ + gn;  // decision margin; samp == (mar > 0)
            bool deferred = false;
            if (fabsf(mar) < FIXTH) {
                int slot = atomicAdd(flagcnt, 1);
                if (slot < FLAGCAP) {
                    flaglist[slot] = pos;
                    deferred = true;  // k_fix decides + writes this edge
                }
            }
            if (!deferred) {
                const float pre = 1.0f / (1.0f + expf(-sc_));
                const bool samp = mar > 0.0f;
                const float ewo = (LAYER == 0) ? ewin[e] : ew_csr[pos];
                const float ewn = samp ? alpha * ewo + (1.0f - alpha) * pre : 0.0f;
                ew_csr[pos] = ewn;
                if (LAYER == NL - 1) {
                    out[OUT_EW + (size_t)e] = ewn;
                    out[OUT_PA + (size_t)e] = pre;
                }
            }
        }
        __syncthreads();
    }
}

// ---- exact f64 re-decision for near-threshold edges (one wave per edge) ----
template <int LAYER>
__global__ __launch_bounds__(256) void k_fix(const float* __restrict__ xsrc,
                                             const int* __restrict__ src_csr,
                                             const int* __restrict__ dst_csr,
                                             const int* __restrict__ eord,
                                             const float* __restrict__ ewin,
                                             float* __restrict__ ew_csr,
                                             const float* __restrict__ unoise,
                                             const float* __restrict__ epW1,
                                             const float* __restrict__ epb1,
                                             const float* __restrict__ epW2,
                                             const float* __restrict__ epb2,
                                             const float* __restrict__ alphap,
                                             const float* __restrict__ Pb32,
                                             const float* __restrict__ Pc32,
                                             const int* __restrict__ flagcnt,
                                             const int* __restrict__ flaglist,
                                             float* __restrict__ out) {
    const int n = min(flagcnt[0], FLAGCAP);
    __shared__ float dxs[4][D];
    const int w = threadIdx.x >> 6, lane = threadIdx.x & 63;
    const int nw = gridDim.x * 4;
    for (int i = blockIdx.x * 4 + w; i < n; i += nw) {
        const int pos = flaglist[i];
        const int s = src_csr[pos], d = dst_csr[pos];
        // |dx| from the same f32 inputs the main kernel staged
        dxs[w][lane] = fabsf(xsrc[(size_t)d * D + lane] - xsrc[(size_t)s * D + lane]);
        // wave-internal broadcast (same-wave DS in-order)
        double h = 0.0;
#pragma unroll
        for (int k = 0; k < D; ++k) h += (double)dxs[w][k] * (double)epW1[k * D + lane];
        h += (double)Pb32[(size_t)d * D + lane] + (double)Pc32[(size_t)s * D + lane] +
             (double)epb1[lane];
        double part = (h > 0.0) ? h * (double)epW2[lane] : 0.0;
#pragma unroll
        for (int off = 32; off; off >>= 1) part += __shfl_xor(part, off);
        if (lane == 0) {
            const double sc_ = part + (double)epb2[0];
            const int e = eord[pos];
            const double u = (double)unoise[(size_t)LAYER * NE + e];
            const double gn = log(u) - log1p(-u);
            const double pre = 1.0 / (1.0 + exp(-sc_));
            const bool samp = (sc_ + gn) > 0.0;
            const double ewo = (LAYER == 0) ? (double)ewin[e] : (double)ew_csr[pos];
            const double alpha = (double)alphap[0];
            const double ewn = samp ? alpha * ewo + (1.0 - alpha) * pre : 0.0;
            ew_csr[pos] = (float)ewn;
            if (LAYER == NL - 1) {
                out[OUT_EW + (size_t)e] = (float)ewn;
                out[OUT_PA + (size_t)e] = (float)pre;
            }
        }
    }
}

// ---- node update: CSR gather-aggregate + GIN mlp + relu + BN partials ----
// xsrc: f32 node rows (xin for layer 0, x32 mirror for layer 1). Each wave
// processes a node PAIR with interleaved 4-wide groups: 8 named-register
// gathers in flight, no arrays (nothing to spill), wave-uniform branches.
// acc + GIN matvec in f64.
template <int LAYER>
__global__ __launch_bounds__(256) void k_nodeup(const float* __restrict__ xsrc,
                                                const float* __restrict__ ew_csr,
                                                const int* __restrict__ src_csr,
                                                const int* __restrict__ rowptr,
                                                const float* __restrict__ ginW,
                                                const float* __restrict__ ginB,
                                                double* __restrict__ xh,
                                                double* __restrict__ bnacc) {
    __shared__ float wg[D * D];
    __shared__ double rowbuf[4][D];
    const int t = threadIdx.x, w = t >> 6, j = t & 63;
    for (int idx = t; idx < D * D; idx += 256) wg[idx] = ginW[LAYER * D * D + idx];
    const double bj = (double)ginB[LAYER * D + j];
    __syncthreads();
    double s1 = 0.0, s2 = 0.0;
    const int wid = blockIdx.x * 4 + w;
    const int nwaves = gridDim.x * 4;  // 8192
    for (int na = wid; na < NN; na += 2 * nwaves) {
        const int nb = na + nwaves;  // < NN (NN = 8 * nwaves)
        const int rsa = rowptr[na], rea = rowptr[na + 1];
        const int rsb = rowptr[nb], reb = rowptr[nb + 1];
        double acca = (double)xsrc[(size_t)na * D + j];
        double accb = (double)xsrc[(size_t)nb * D + j];
        int ka = rsa, kb = rsb;
        // interleaved main loop: 8 gathers in flight
        while (ka + 4 <= rea && kb + 4 <= reb) {
            const float wa0 = ew_csr[ka], wa1 = ew_csr[ka + 1];
            const float wa2 = ew_csr[ka + 2], wa3 = ew_csr[ka + 3];
            const int sa0 = src_csr[ka], sa1 = src_csr[ka + 1];
            const int sa2 = src_csr[ka + 2], sa3 = src_csr[ka + 3];
            const float wb0 = ew_csr[kb], wb1 = ew_csr[kb + 1];
            const float wb2 = ew_csr[kb + 2], wb3 = ew_csr[kb + 3];
            const int sb0 = src_csr[kb], sb1 = src_csr[kb + 1];
            const int sb2 = src_csr[kb + 2], sb3 = src_csr[kb + 3];
            const float xa0 = xsrc[(size_t)sa0 * D + j], xa1 = xsrc[(size_t)sa1 * D + j];
            const float xa2 = xsrc[(size_t)sa2 * D + j], xa3 = xsrc[(size_t)sa3 * D + j];
            const float xb0 = xsrc[(size_t)sb0 * D + j], xb1 = xsrc[(size_t)sb1 * D + j];
            const float xb2 = xsrc[(size_t)sb2 * D + j], xb3 = xsrc[(size_t)sb3 * D + j];
            acca += (double)wa0 * (double)xa0;
            acca += (double)wa1 * (double)xa1;
            acca += (double)wa2 * (double)xa2;
            acca += (double)wa3 * (double)xa3;
            accb += (double)wb0 * (double)xb0;
            accb += (double)wb1 * (double)xb1;
            accb += (double)wb2 * (double)xb2;
            accb += (double)wb3 * (double)xb3;
            ka += 4;
            kb += 4;
        }
        // drain a (4-wide then scalar)
        for (; ka + 4 <= rea; ka += 4) {
            const float w0 = ew_csr[ka], w1 = ew_csr[ka + 1];
            const float w2 = ew_csr[ka + 2], w3 = ew_csr[ka + 3];
            const int s0 = src_csr[ka], s1_ = src_csr[ka + 1];
            const int s2_ = src_csr[ka + 2], s3 = src_csr[ka + 3];
            const float x0 = xsrc[(size_t)s0 * D + j], x1 = xsrc[(size_t)s1_ * D + j];
            const float x2 = xsrc[(size_t)s2_ * D + j], x3 = xsrc[(size_t)s3 * D + j];
            acca += (double)w0 * (double)x0;
            acca += (double)w1 * (double)x1;
            acca += (double)w2 * (double)x2;
            acca += (double)w3 * (double)x3;
        }
        for (; ka < rea; ++ka)
            acca += (double)ew_csr[ka] * (double)xsrc[(size_t)src_csr[ka] * D + j];
        // drain b
        for (; kb + 4 <= reb; kb += 4) {
            const float w0 = ew_csr[kb], w1 = ew_csr[kb + 1];
            const float w2 = ew_csr[kb + 2], w3 = ew_csr[kb + 3];
            const int s0 = src_csr[kb], s1_ = src_csr[kb + 1];
            const int s2_ = src_csr[kb + 2], s3 = src_csr[kb + 3];
            const float x0 = xsrc[(size_t)s0 * D + j], x1 = xsrc[(size_t)s1_ * D + j];
            const float x2 = xsrc[(size_t)s2_ * D + j], x3 = xsrc[(size_t)s3 * D + j];
            accb += (double)w0 * (double)x0;
            accb += (double)w1 * (double)x1;
            accb += (double)w2 * (double)x2;
            accb += (double)w3 * (double)x3;
        }
        for (; kb < reb; ++kb)
            accb += (double)ew_csr[kb] * (double)xsrc[(size_t)src_csr[kb] * D + j];

        // matvec a (same-wave LDS in-order => rowbuf reuse is safe)
        rowbuf[w][j] = acca;
        double ha = bj;
#pragma unroll
        for (int i = 0; i < D; ++i) ha += rowbuf[w][i] * (double)wg[i * D + j];
        ha = ha > 0.0 ? ha : 0.0;
        xh[(size_t)na * D + j] = ha;
        s1 += ha;
        s2 += ha * ha;
        // matvec b
        rowbuf[w][j] = accb;
        double hb = bj;
#pragma unroll
        for (int i = 0; i < D; ++i) hb += rowbuf[w][i] * (double)wg[i * D + j];
        hb = hb > 0.0 ? hb : 0.0;
        xh[(size_t)nb * D + j] = hb;
        s1 += hb;
        s2 += hb * hb;
    }
    atomAdd64(&bnacc[j], s1);
    atomAdd64(&bnacc[64 + j], s2);
}

// ---- BN finalize ----
__global__ __launch_bounds__(64) void k_bnfin(int layer, const float* __restrict__ gamma,
                                              const float* __restrict__ beta,
                                              const double* __restrict__ bnacc,
                                              double* __restrict__ bnsc) {
    int j = threadIdx.x;
    double mu = bnacc[j] * (1.0 / NN);
    double var = bnacc[64 + j] * (1.0 / NN) - mu * mu;
    double sc = (double)gamma[layer * D + j] / sqrt(var + 1e-5);
    bnsc[j] = sc;
    bnsc[64 + j] = (double)beta[layer * D + j] - mu * sc;
}

// ---- BN apply -> x64 (+x32 mirror for edge/nodeup staging; final out) ----
template <int LAYER>
__global__ __launch_bounds__(256) void k_bnapply(const double* __restrict__ bnsc,
                                                 const double* __restrict__ xh,
                                                 double* __restrict__ x64,
                                                 float* __restrict__ x32,
                                                 float* __restrict__ out) {
    size_t stride = (size_t)gridDim.x * 256;
    for (size_t i = (size_t)blockIdx.x * 256 + threadIdx.x; i < (size_t)NN * D; i += stride) {
        int j = (int)(i & 63);
        double v = bnsc[j] * xh[i] + bnsc[64 + j];
        x64[i] = v;
        if (LAYER == 0) x32[i] = (float)v;
        if (LAYER == NL - 1) out[OUT_X + i] = (float)v;
    }
}

// ---- attention pooling, parallelized: 4 kernels ----
__global__ __launch_bounds__(256) void k_att1(const double* __restrict__ x64,
                                              const double* __restrict__ c64,
                                              double* __restrict__ sc,
                                              double* __restrict__ bmax) {
    const int blk = blockIdx.x, t = threadIdx.x, w = t >> 6, lane = t & 63;
    const int g = blk >> 6;
    __shared__ double wmax[4];
    const double cj = c64[g * D + lane];
    double locmax = -1e300;
    for (int m = 0; m < 16; ++m) {
        const int n = blk * 64 + w * 16 + m;
        double v = x64[(size_t)n * D + lane] * cj;
#pragma unroll
        for (int off = 32; off; off >>= 1) v += __shfl_xor(v, off);
        if (lane == 0) sc[n] = v;
        locmax = fmax(locmax, v);
    }
    if (lane == 0) wmax[w] = locmax;
    __syncthreads();
    if (t == 0) bmax[blk] = fmax(fmax(wmax[0], wmax[1]), fmax(wmax[2], wmax[3]));
}

__global__ __launch_bounds__(64) void k_att2(const double* __restrict__ bmax,
                                             double* __restrict__ mxg,
                                             double* __restrict__ num,
                                             double* __restrict__ den) {
    const int g = blockIdx.x, t = threadIdx.x;
    double m = bmax[g * 64 + t];
#pragma unroll
    for (int off = 32; off; off >>= 1) m = fmax(m, __shfl_xor(m, off));
    if (t == 0) {
        mxg[g] = m;
        den[g] = 0.0;
    }
    num[g * D + t] = 0.0;
}

__global__ __launch_bounds__(256) void k_att3(const double* __restrict__ x64,
                                              const double* __restrict__ sc,
                                              const double* __restrict__ mxg,
                                              double* __restrict__ num,
                                              double* __restrict__ den) {
    const int blk = blockIdx.x, t = threadIdx.x, w = t >> 6, lane = t & 63;
    const int g = blk >> 6;
    __shared__ double cp[4][D];
    __shared__ double wes[4];
    const double mx = mxg[g];
    double accj = 0.0, esum = 0.0;
    for (int m = 0; m < 16; ++m) {
        const int n = blk * 64 + w * 16 + m;
        const double e = exp(sc[n] - mx);
        accj += e * x64[(size_t)n * D + lane];
        esum += e;
    }
    cp[w][lane] = accj;
    if (lane == 0) wes[w] = esum;
    __syncthreads();
    if (t < D) {
        atomAdd64(&num[g * D + t], cp[0][t] + cp[1][t] + cp[2][t] + cp[3][t]);
        if (t == 0) atomAdd64(&den[g], wes[0] + wes[1] + wes[2] + wes[3]);
    }
}

__global__ __launch_bounds__(64) void k_att4(const double* __restrict__ num,
                                             const double* __restrict__ den,
                                             double* __restrict__ c64) {
    const int g = blockIdx.x, t = threadIdx.x;
    c64[g * D + t] = num[g * D + t] / den[g];
}

// ---- head: relu(x@W1+b1)@W2+b2 for all nodes + 16 centroid rows (f32) ----
__global__ __launch_bounds__(256) void k_head(const double* __restrict__ x64,
                                              const double* __restrict__ c64,
                                              const float* __restrict__ hW1,
                                              const float* __restrict__ hb1,
                                              const float* __restrict__ hW2,
                                              const float* __restrict__ hb2,
                                              float* __restrict__ out) {
    __shared__ float w1[D * D];
    __shared__ float w2[D * D];
    __shared__ float xr[4][D];
    __shared__ float hr[4][D];
    int tid = threadIdx.x, w = tid >> 6, j = tid & 63;
    for (int idx = tid; idx < D * D; idx += 256) {
        w1[idx] = hW1[idx];
        w2[idx] = hW2[idx];
    }
    const float b1j = hb1[j];
    const float b2j = hb2[j];
    __syncthreads();
    const int ROWS = NN + BSZ;
    for (int grp = blockIdx.x; grp * 4 < ROWS; grp += gridDim.x) {
        int r = grp * 4 + w;
        bool valid = r < ROWS;
        float xv = 0.f;
        if (valid)
            xv = (r < NN) ? (float)x64[(size_t)r * D + j] : (float)c64[(size_t)(r - NN) * D + j];
        xr[w][j] = xv;
        __syncthreads();
        if (valid) {
            float h = b1j;
#pragma unroll
            for (int i = 0; i < D; ++i) h += xr[w][i] * w1[i * D + j];
            hr[w][j] = h > 0.f ? h : 0.f;
        }
        __syncthreads();
        if (valid) {
            float o = b2j;
#pragma unroll
            for (int i = 0; i < D; ++i) o += hr[w][i] * w2[i * D + j];
            if (r < NN) {
                out[OUT_XL + (size_t)r * D + j] = o;
            } else {
                size_t cr = (size_t)(r - NN) * D + j;
                out[OUT_CL + cr] = o;
                out[OUT_C + cr] = (float)c64[cr];
            }
        }
        __syncthreads();
    }
}

extern "C" void kernel_launch(void* const* d_in, const int* in_sizes, int n_in,
                              void* d_out, int out_size, void* d_ws, size_t ws_size,
                              hipStream_t stream) {
    const float* xin    = (const float*)d_in[0];
    const int*   ei     = (const int*)d_in[1];
    const float* ewin   = (const float*)d_in[2];
    const float* unoise = (const float*)d_in[5];
    const float* epW1   = (const float*)d_in[6];
    const float* epb1   = (const float*)d_in[7];
    const float* epW2   = (const float*)d_in[8];
    const float* epb2   = (const float*)d_in[9];
    const float* alphap = (const float*)d_in[10];
    const float* ginW   = (const float*)d_in[11];
    const float* ginB   = (const float*)d_in[12];
    const float* bng    = (const float*)d_in[13];
    const float* bnb    = (const float*)d_in[14];
    const float* hW1    = (const float*)d_in[15];
    const float* hb1    = (const float*)d_in[16];
    const float* hW2    = (const float*)d_in[17];
    const float* hb2    = (const float*)d_in[18];
    float* out = (float*)d_out;
    const int* esrc = ei;
    const int* edst = ei + NE;

    char* ws = (char*)d_ws;
    const size_t SZ = (size_t)NN * D * sizeof(double);  // 33554432
    double* x64  = (double*)(ws);
    // Pb/Pc (k_P->k_edge) and xh (k_nodeup->k_bnapply): disjoint live ranges.
    float*  Pb32 = (float*)(ws + SZ);
    float*  Pc32 = (float*)(ws + SZ + SZ / 2);
    double* xh   = (double*)(ws + SZ);
    float*  x32  = (float*)(ws + 2 * SZ);                       // NN*D*4 = 16MB
    float*  ew_csr = (float*)(ws + 2 * SZ + SZ / 2);            // NE*4 (slot is NE*8)
    double* sc   = (double*)(ws + 2 * SZ + SZ / 2 + (size_t)NE * 8);  // NN*8
    char*   p    = ws + 2 * SZ + SZ / 2 + (size_t)NE * 8 + (size_t)NN * 8;
    double* c64  = (double*)p;          p += BSZ * D * 8;
    double* qb   = (double*)p;          p += BSZ * D * 8;
    double* qc   = (double*)p;          p += BSZ * D * 8;
    double* bnacc = (double*)p;         p += 128 * 8;
    double* bnsc  = (double*)p;         p += 128 * 8;
    double* bmax  = (double*)p;         p += 1024 * 8;
    double* mxg   = (double*)p;         p += 16 * 8;
    double* num   = (double*)p;         p += BSZ * D * 8;
    double* den   = (double*)p;         p += 16 * 8;
    // CSR
    int* cnt     = (int*)p;             p += (size_t)NN * 4;
    int* rowptr  = (int*)p;             p += (size_t)(NN + 1) * 4 + 4;
    int* cursor  = (int*)p;             p += (size_t)NN * 4;
    int* bsum    = (int*)p;             p += 256 * 4;
    int* eord    = (int*)p;             p += (size_t)NE * 4;
    int* src_csr = (int*)p;             p += (size_t)NE * 4;
    int* dst_csr = (int*)p;             p += (size_t)NE * 4;
    // near-threshold fixup list
    int* flagcnt  = (int*)p;            p += 8;
    int* flaglist = (int*)p;            p += (size_t)FLAGCAP * 4;

    // ---- CSR build (dst static) ----
    hipMemsetAsync(cnt, 0, (size_t)NN * 4, stream);
    k_deg<<<1024, 256, 0, stream>>>(edst, cnt);
    k_scan1<<<256, 256, 0, stream>>>(cnt, rowptr, bsum);
    k_scan2<<<1, 256, 0, stream>>>(bsum);
    k_scan3<<<256, 256, 0, stream>>>(bsum, rowptr, cursor);
    k_fill<<<1024, 256, 0, stream>>>(esrc, edst, cursor, eord, src_csr, dst_csr);

    k_centroid0<<<BSZ, 256, 0, stream>>>(xin, c64);

    // ---------------- layer 0 ----------------
    k_qbc<<<4, 256, 0, stream>>>(c64, epW1, qb, qc);
    k_P<0><<<1024, 256, 0, stream>>>(xin, x64, epW1, qb, qc, Pb32, Pc32, bnacc);
    hipMemsetAsync(flagcnt, 0, 4, stream);
    k_edge<0><<<2048, 256, 0, stream>>>(xin, src_csr, dst_csr, eord, ewin, ew_csr, unoise,
                                        epW1, epb1, epW2, epb2, alphap, Pb32, Pc32,
                                        flagcnt, flaglist, out);
    k_fix<0><<<64, 256, 0, stream>>>(xin, src_csr, dst_csr, eord, ewin, ew_csr, unoise,
                                     epW1, epb1, epW2, epb2, alphap, Pb32, Pc32,
                                     flagcnt, flaglist, out);
    k_nodeup<0><<<2048, 256, 0, stream>>>(xin, ew_csr, src_csr, rowptr, ginW, ginB,
                                          xh, bnacc);
    k_bnfin<<<1, 64, 0, stream>>>(0, bng, bnb, bnacc, bnsc);
    k_bnapply<0><<<2048, 256, 0, stream>>>(bnsc, xh, x64, x32, out);
    k_att1<<<1024, 256, 0, stream>>>(x64, c64, sc, bmax);
    k_att2<<<16, 64, 0, stream>>>(bmax, mxg, num, den);
    k_att3<<<1024, 256, 0, stream>>>(x64, sc, mxg, num, den);
    k_att4<<<16, 64, 0, stream>>>(num, den, c64);

    // ---------------- layer 1 ----------------
    k_qbc<<<4, 256, 0, stream>>>(c64, epW1, qb, qc);
    k_P<1><<<1024, 256, 0, stream>>>(xin, x64, epW1, qb, qc, Pb32, Pc32, bnacc);
    hipMemsetAsync(flagcnt, 0, 4, stream);
    k_edge<1><<<2048, 256, 0, stream>>>(x32, src_csr, dst_csr, eord, ewin, ew_csr, unoise,
                                        epW1, epb1, epW2, epb2, alphap, Pb32, Pc32,
                                        flagcnt, flaglist, out);
    k_fix<1><<<64, 256, 0, stream>>>(x32, src_csr, dst_csr, eord, ewin, ew_csr, unoise,
                                     epW1, epb1, epW2, epb2, alphap, Pb32, Pc32,
                                     flagcnt, flaglist, out);
    k_nodeup<1><<<2048, 256, 0, stream>>>(x32, ew_csr, src_csr, rowptr, ginW, ginB,
                                          xh, bnacc);
    k_bnfin<<<1, 64, 0, stream>>>(1, bng, bnb, bnacc, bnsc);
    k_bnapply<1><<<2048, 256, 0, stream>>>(bnsc, xh, x64, x32, out);
    k_att1<<<1024, 256, 0, stream>>>(x64, c64, sc, bmax);
    k_att2<<<16, 64, 0, stream>>>(bmax, mxg, num, den);
    k_att3<<<1024, 256, 0, stream>>>(x64, sc, mxg, num, den);
    k_att4<<<16, 64, 0, stream>>>(num, den, c64);

    // ---------------- heads + centroid output ----------------
    k_head<<<2048, 256, 0, stream>>>(x64, c64, hW1, hb1, hW2, hb2, out);
}